// Round 8
// baseline (253.193 us; speedup 1.0000x reference)
//
#include <hip/hip_runtime.h>
#include <hip/hip_bf16.h>
#include <stdint.h>

// Problem constants
// x: [8,32,32,32] f32; G=16 -> pooled [8,32,16,16]; Pg=15, P=225; D=130; 2D=260
// HIDDEN=256, NOUT=128. leaky_relu slope 0.01.
#define NB 8
#define NP 225      // patches per image
#define PGRID 15    // 15x15 patch grid
#define DH 256      // hidden
#define DIN 130     // per-node feature dim

typedef short s16x8 __attribute__((ext_vector_type(8)));   // 8 bf16 frag (4 VGPRs)
typedef float f32x4 __attribute__((ext_vector_type(4)));

static __device__ __forceinline__ uint16_t f2bf(float f) {
    union { float f; uint32_t u; } a; a.f = f;
    uint32_t u = a.u;
    return (uint16_t)((u + 0x7FFFu + ((u >> 16) & 1u)) >> 16);  // RNE
}
// Plain scalar casts: compiler fuses pairs into v_cvt_pk_bf16_f32 (m240).
static __device__ __forceinline__ uint32_t pack2(float a, float b) {
    union { __hip_bfloat16 h[2]; uint32_t u; } cv;
    cv.h[0] = __float2bfloat16(a);
    cv.h[1] = __float2bfloat16(b);
    return cv.u;
}
static __device__ __forceinline__ float lrelu(float x) { return fmaxf(x, 0.01f * x); }

// ---------------------------------------------------------------------------
// K1 (fused prep): blocks 0..359 = pool+patch+U/V projection (+ accg zeroing);
//                  blocks 360..391 = W1 repack to fragment-linear bf16.
//   U[b,p,n] = feats[b,p,:] @ W0[0:130, n] + b0[n]
//   V[b,p,n] = feats[b,p,:] @ W0[130:260, n]
//   W1F[((nf*8+ks)*64+l)*8+e] = bf16(W1[k,n]), n=nf*16+(l&15), k=ks*32+(l>>4)*8+e
__global__ void prep_kernel(const float* __restrict__ x, const float* __restrict__ W0,
                            const float* __restrict__ b0, const float* __restrict__ W1,
                            float* __restrict__ U, float* __restrict__ V,
                            uint16_t* __restrict__ W1F, float* __restrict__ accg) {
    int blk = blockIdx.x;
    if (blk >= 360) {
        // ---- W1 repack
        int t = (blk - 360) * 256 + threadIdx.x;   // 8192 threads = 128 slots * 64 lanes
        int slot = t >> 6, l = t & 63;
        int nf = slot >> 3, ks = slot & 7;
        int n = nf * 16 + (l & 15);
        int kb = l >> 4;
        uint32_t pk[4];
        #pragma unroll
        for (int e2 = 0; e2 < 4; ++e2) {
            int k = ks * 32 + kb * 8 + 2 * e2;
            uint32_t lo = f2bf(W1[k * DH + n]);
            uint32_t hi = f2bf(W1[(k + 1) * DH + n]);
            pk[e2] = lo | (hi << 16);
        }
        reinterpret_cast<uint4*>(W1F)[t] = make_uint4(pk[0], pk[1], pk[2], pk[3]);
        return;
    }
    // ---- U/V projection
    int bb = blk / 45;
    int p0 = (blk % 45) * 5;
    if (blk % 45 == 0) accg[bb * DH + threadIdx.x] = 0.0f;   // replaces memset
    __shared__ float fl[5][DIN];
    int t = threadIdx.x;
    for (int idx = t; idx < 5 * DIN; idx += 256) {
        int pp = idx / DIN, f = idx % DIN;
        int p = p0 + pp;
        int r = p / PGRID, c = p % PGRID;
        float val;
        if (f < 128) {
            int ch = f >> 2, q = f & 3, ki = q >> 1, kj = q & 1;
            int R = r + ki, C = c + kj;                 // pooled coords (0..15)
            const float* xp = x + (((size_t)bb * 32 + ch) * 32 + 2 * R) * 32 + 2 * C;
            val = 0.25f * (xp[0] + xp[1] + xp[32] + xp[33]);
        } else {
            val = (f == 128) ? (float)(c - 7) : (float)(r - 7);  // cx, cy
        }
        fl[pp][f] = val;
    }
    __syncthreads();
    int n = t;  // 0..255
    float u[5] = {0, 0, 0, 0, 0}, v[5] = {0, 0, 0, 0, 0};
    for (int k = 0; k < DIN; ++k) {
        float wa = W0[k * DH + n];
        float wb = W0[(DIN + k) * DH + n];
        #pragma unroll
        for (int pp = 0; pp < 5; ++pp) {
            float f = fl[pp][k];
            u[pp] = fmaf(f, wa, u[pp]);
            v[pp] = fmaf(f, wb, v[pp]);
        }
    }
    float bb0 = b0[n];
    #pragma unroll
    for (int pp = 0; pp < 5; ++pp) {
        size_t base = ((size_t)bb * NP + p0 + pp) * DH + n;
        U[base] = u[pp] + bb0;  // fold b0 into U
        V[base] = v[pp];
    }
}

// ---------------------------------------------------------------------------
// K2: main relational GEMM + reduce. BARRIER-FREE register-A design.
// Block = (batch, j-tile 16, chunk of <=5 i-tiles), 4 waves, fully independent
// after the single Upad-staging barrier.
// Wave w: N-slice n in [w*64, w*64+64) with persistent bv (128 VGPR).
// Per iter, ks-outer loop: U-frag from LDS (mf-invariant, hoisted), V from
// global (imm-offset b128, L1-shared across the 4 waves), A-frag built in
// registers (one live frag), 4 MFMA consume it immediately. No A staging,
// no barriers -> the 2 resident waves/SIMD overlap VALU-build with MFMA.
// Epilogue: h=lrelu(acc), psum += h*jmask (fma-mask), wave-uniform mf skip.
__global__ __launch_bounds__(256, 2) void main_kernel(
        const float* __restrict__ U, const float* __restrict__ V,
        const uint16_t* __restrict__ W1F, const float* __restrict__ b1,
        float* __restrict__ accg) {
    __shared__ float Upad[16 * 260];  // 16.25 KB, stride 260: 2-way max on reads
    const int JT = 15, CHUNKS = 12, TILESPC = 5;  // 11*5+2 = 57 i-tiles
    int blk = blockIdx.x;
    int bb = blk / (JT * CHUNKS);
    int rem = blk % (JT * CHUNKS);
    int jt = rem / CHUNKS, ch = rem % CHUNKS;
    int j0 = jt * 16;
    int tile0 = ch * TILESPC;
    int nt = min(TILESPC, 57 - tile0);
    int t = threadIdx.x, l = t & 63, w = t >> 6;

    // ---- stage U tile once (coalesced global reads)
    {
        int jj = t >> 4, kk = (t & 15) * 16;
        int jc = j0 + jj; if (jc >= NP) jc = NP - 1;   // clamp; jmask kills later
        const float* src = U + ((size_t)bb * NP + jc) * DH + kk;
        #pragma unroll
        for (int e = 0; e < 4; ++e)
            *reinterpret_cast<float4*>(&Upad[jj * 260 + kk + 4 * e]) =
                *reinterpret_cast<const float4*>(src + 4 * e);
    }
    // ---- persistent B fragments (wave's N=64 slice): 32 frags = 128 VGPR
    s16x8 bv[4][8];
    const s16x8* Bp = reinterpret_cast<const s16x8*>(W1F);
    #pragma unroll
    for (int nf = 0; nf < 4; ++nf)
        #pragma unroll
        for (int ks = 0; ks < 8; ++ks)
            bv[nf][ks] = Bp[((w * 4 + nf) * 8 + ks) * 64 + l];
    float b1v[4];
    #pragma unroll
    for (int nf = 0; nf < 4; ++nf) b1v[nf] = b1[w * 64 + nf * 16 + (l & 15)];
    int rowg = l >> 4;
    float jmask[4];
    #pragma unroll
    for (int r = 0; r < 4; ++r) jmask[r] = (j0 + rowg * 4 + r) < NP ? 1.0f : 0.0f;
    float psum[4] = {0.f, 0.f, 0.f, 0.f};
    int kb = l >> 4;
    const float* Urow = &Upad[(l & 15) * 260 + kb * 8];
    const float* Vbb = V + (size_t)bb * NP * DH + kb * 8;
    __syncthreads();   // the only barrier

    for (int itl = 0; itl < nt; ++itl) {
        int i0 = (tile0 + itl) * 4;
        // per-mf clamped V row base (handles i0+mf >= NP without OOB)
        const float* Vp[4];
        #pragma unroll
        for (int mf = 0; mf < 4; ++mf) {
            int ic = i0 + mf; if (ic >= NP) ic = NP - 1;
            Vp[mf] = Vbb + (size_t)ic * DH;
        }
        f32x4 acc[4][4];
        #pragma unroll
        for (int mf = 0; mf < 4; ++mf)
            #pragma unroll
            for (int nf = 0; nf < 4; ++nf)
                acc[mf][nf] = (f32x4){b1v[nf], b1v[nf], b1v[nf], b1v[nf]};

        #pragma unroll
        for (int ks = 0; ks < 8; ++ks) {
            float4 ua = *reinterpret_cast<const float4*>(Urow + ks * 32);
            float4 ub = *reinterpret_cast<const float4*>(Urow + ks * 32 + 4);
            #pragma unroll
            for (int mf = 0; mf < 4; ++mf) {
                const float* vp = Vp[mf] + ks * 32;
                float4 va = *reinterpret_cast<const float4*>(vp);
                float4 vb = *reinterpret_cast<const float4*>(vp + 4);
                union { uint32_t u[4]; s16x8 v; } af;
                af.u[0] = pack2(lrelu(ua.x + va.x), lrelu(ua.y + va.y));
                af.u[1] = pack2(lrelu(ua.z + va.z), lrelu(ua.w + va.w));
                af.u[2] = pack2(lrelu(ub.x + vb.x), lrelu(ub.y + vb.y));
                af.u[3] = pack2(lrelu(ub.z + vb.z), lrelu(ub.w + vb.w));
                #pragma unroll
                for (int nf = 0; nf < 4; ++nf)
                    acc[mf][nf] = __builtin_amdgcn_mfma_f32_16x16x32_bf16(
                        af.v, bv[nf][ks], acc[mf][nf], 0, 0, 0);
            }
        }

        // ---- epilogue: lrelu + fma-masked row-sum (wave-uniform mf skip)
        #pragma unroll
        for (int mf = 0; mf < 4; ++mf) {
            if (i0 + mf < NP) {
                #pragma unroll
                for (int r = 0; r < 4; ++r) {
                    #pragma unroll
                    for (int nf = 0; nf < 4; ++nf) {
                        float a = acc[mf][nf][r];
                        float h = fmaxf(a, 0.01f * a);
                        psum[nf] = fmaf(h, jmask[r], psum[nf]);
                    }
                }
            }
        }
    }

    // ---- block-level reduce + one atomicAdd set
    #pragma unroll
    for (int nf = 0; nf < 4; ++nf) {
        psum[nf] += __shfl_xor(psum[nf], 16);
        psum[nf] += __shfl_xor(psum[nf], 32);
    }
    if (l < 16) {
        #pragma unroll
        for (int nf = 0; nf < 4; ++nf)
            atomicAdd(&accg[bb * DH + w * 64 + nf * 16 + l], psum[nf]);
    }
}

// ---------------------------------------------------------------------------
// K3: out[b,o] = (accg[b,:]/P^2) @ Wout + bout
__global__ void out_kernel(const float* __restrict__ accg, const float* __restrict__ Wout,
                           const float* __restrict__ bout, float* __restrict__ out) {
    int bb = blockIdx.x;
    int o = threadIdx.x;  // 0..127
    float s = 0.f;
    for (int n = 0; n < DH; ++n)
        s = fmaf(accg[bb * DH + n], Wout[n * 128 + o], s);
    out[bb * 128 + o] = s * (1.0f / 50625.0f) + bout[o];
}

// ---------------------------------------------------------------------------
extern "C" void kernel_launch(void* const* d_in, const int* in_sizes, int n_in,
                              void* d_out, int out_size, void* d_ws, size_t ws_size,
                              hipStream_t stream) {
    const float* x    = (const float*)d_in[0];
    const float* W0   = (const float*)d_in[1];
    const float* b0   = (const float*)d_in[2];
    const float* W1   = (const float*)d_in[3];
    const float* b1   = (const float*)d_in[4];
    const float* Wout = (const float*)d_in[5];
    const float* bout = (const float*)d_in[6];
    float* out = (float*)d_out;

    char* ws = (char*)d_ws;
    float*    U    = (float*)(ws);                            // 8*225*256*4 = 1,843,200 B
    float*    V    = (float*)(ws + 1843200);                  // 1,843,200 B
    uint16_t* W1F  = (uint16_t*)(ws + 2 * 1843200);           // 131,072 B
    float*    accg = (float*)(ws + 2 * 1843200 + 131072);     // 8*256*4 = 8,192 B

    prep_kernel<<<392, 256, 0, stream>>>(x, W0, b0, W1, U, V, W1F, accg);
    main_kernel<<<NB * 15 * 12, 256, 0, stream>>>(U, V, W1F, b1, accg);
    out_kernel<<<NB, 128, 0, stream>>>(accg, Wout, bout, out);
}

// Round 9
// 252.714 us; speedup vs baseline: 1.0019x; 1.0019x over previous
//
#include <hip/hip_runtime.h>
#include <hip/hip_bf16.h>
#include <stdint.h>

// Problem constants
// x: [8,32,32,32] f32; G=16 -> pooled [8,32,16,16]; Pg=15, P=225; D=130; 2D=260
// HIDDEN=256, NOUT=128. leaky_relu slope 0.01.
#define NB 8
#define NP 225      // patches per image
#define PGRID 15    // 15x15 patch grid
#define DH 256      // hidden
#define DIN 130     // per-node feature dim

typedef short    s16x8 __attribute__((ext_vector_type(8)));   // 8 bf16 frag (4 VGPRs)
typedef float    f32x4 __attribute__((ext_vector_type(4)));
typedef uint32_t u32x4 __attribute__((ext_vector_type(4)));

static __device__ __forceinline__ uint16_t f2bf(float f) {
    union { float f; uint32_t u; } a; a.f = f;
    uint32_t u = a.u;
    return (uint16_t)((u + 0x7FFFu + ((u >> 16) & 1u)) >> 16);  // RNE
}
// Plain scalar casts: compiler fuses pairs into v_cvt_pk_bf16_f32 (m240).
static __device__ __forceinline__ uint32_t pack2(float a, float b) {
    union { __hip_bfloat16 h[2]; uint32_t u; } cv;
    cv.h[0] = __float2bfloat16(a);
    cv.h[1] = __float2bfloat16(b);
    return cv.u;
}
static __device__ __forceinline__ float lrelu(float x) { return fmaxf(x, 0.01f * x); }

// ---------------------------------------------------------------------------
// K1 (fused prep): blocks 0..359 = pool+patch+U/V projection (+ accg zeroing);
//                  blocks 360..391 = W1 repack to fragment-linear bf16.
//   U[b,p,n] = feats[b,p,:] @ W0[0:130, n] + b0[n]
//   V[b,p,n] = feats[b,p,:] @ W0[130:260, n]
//   W1F[((nf*8+ks)*64+l)*8+e] = bf16(W1[k,n]), n=nf*16+(l&15), k=ks*32+(l>>4)*8+e
__global__ void prep_kernel(const float* __restrict__ x, const float* __restrict__ W0,
                            const float* __restrict__ b0, const float* __restrict__ W1,
                            float* __restrict__ U, float* __restrict__ V,
                            uint16_t* __restrict__ W1F, float* __restrict__ accg) {
    int blk = blockIdx.x;
    if (blk >= 360) {
        // ---- W1 repack
        int t = (blk - 360) * 256 + threadIdx.x;   // 8192 threads = 128 slots * 64 lanes
        int slot = t >> 6, l = t & 63;
        int nf = slot >> 3, ks = slot & 7;
        int n = nf * 16 + (l & 15);
        int kb = l >> 4;
        uint32_t pk[4];
        #pragma unroll
        for (int e2 = 0; e2 < 4; ++e2) {
            int k = ks * 32 + kb * 8 + 2 * e2;
            uint32_t lo = f2bf(W1[k * DH + n]);
            uint32_t hi = f2bf(W1[(k + 1) * DH + n]);
            pk[e2] = lo | (hi << 16);
        }
        reinterpret_cast<uint4*>(W1F)[t] = make_uint4(pk[0], pk[1], pk[2], pk[3]);
        return;
    }
    // ---- U/V projection
    int bb = blk / 45;
    int p0 = (blk % 45) * 5;
    if (blk % 45 == 0) accg[bb * DH + threadIdx.x] = 0.0f;   // replaces memset
    __shared__ float fl[5][DIN];
    int t = threadIdx.x;
    for (int idx = t; idx < 5 * DIN; idx += 256) {
        int pp = idx / DIN, f = idx % DIN;
        int p = p0 + pp;
        int r = p / PGRID, c = p % PGRID;
        float val;
        if (f < 128) {
            int ch = f >> 2, q = f & 3, ki = q >> 1, kj = q & 1;
            int R = r + ki, C = c + kj;                 // pooled coords (0..15)
            const float* xp = x + (((size_t)bb * 32 + ch) * 32 + 2 * R) * 32 + 2 * C;
            val = 0.25f * (xp[0] + xp[1] + xp[32] + xp[33]);
        } else {
            val = (f == 128) ? (float)(c - 7) : (float)(r - 7);  // cx, cy
        }
        fl[pp][f] = val;
    }
    __syncthreads();
    int n = t;  // 0..255
    float u[5] = {0, 0, 0, 0, 0}, v[5] = {0, 0, 0, 0, 0};
    for (int k = 0; k < DIN; ++k) {
        float wa = W0[k * DH + n];
        float wb = W0[(DIN + k) * DH + n];
        #pragma unroll
        for (int pp = 0; pp < 5; ++pp) {
            float f = fl[pp][k];
            u[pp] = fmaf(f, wa, u[pp]);
            v[pp] = fmaf(f, wb, v[pp]);
        }
    }
    float bb0 = b0[n];
    #pragma unroll
    for (int pp = 0; pp < 5; ++pp) {
        size_t base = ((size_t)bb * NP + p0 + pp) * DH + n;
        U[base] = u[pp] + bb0;  // fold b0 into U
        V[base] = v[pp];
    }
}

// ---------------------------------------------------------------------------
// K2: main relational GEMM + reduce. BARRIER-FREE register-A design.
// Same as R8 except the A-fragment is built in a u32x4 ext_vector and
// __builtin_bit_cast to s16x8 — R8's union type-pun was alloca'd to scratch
// (FETCH 210MB / WRITE 118MB); ext_vectors stay in SSA registers.
// Block = (batch, j-tile 16, chunk of <=5 i-tiles), 4 waves, independent
// after the single Upad-staging barrier.
// Wave w: N-slice [w*64, w*64+64) with persistent bv (128 regs).
// Per iter, ks-outer: U-frag from LDS (mf-invariant, hoisted), V from global
// (L1-shared), A-frag in registers, 4 MFMA consume immediately. No barriers
// -> co-resident waves overlap VALU-build with MFMA.
__global__ __launch_bounds__(256, 2) void main_kernel(
        const float* __restrict__ U, const float* __restrict__ V,
        const uint16_t* __restrict__ W1F, const float* __restrict__ b1,
        float* __restrict__ accg) {
    __shared__ float Upad[16 * 260];  // 16.25 KB, stride 260: 2-way max on reads
    const int JT = 15, CHUNKS = 12, TILESPC = 5;  // 11*5+2 = 57 i-tiles
    int blk = blockIdx.x;
    int bb = blk / (JT * CHUNKS);
    int rem = blk % (JT * CHUNKS);
    int jt = rem / CHUNKS, ch = rem % CHUNKS;
    int j0 = jt * 16;
    int tile0 = ch * TILESPC;
    int nt = min(TILESPC, 57 - tile0);
    int t = threadIdx.x, l = t & 63, w = t >> 6;

    // ---- stage U tile once (coalesced global reads)
    {
        int jj = t >> 4, kk = (t & 15) * 16;
        int jc = j0 + jj; if (jc >= NP) jc = NP - 1;   // clamp; jmask kills later
        const float* src = U + ((size_t)bb * NP + jc) * DH + kk;
        #pragma unroll
        for (int e = 0; e < 4; ++e)
            *reinterpret_cast<float4*>(&Upad[jj * 260 + kk + 4 * e]) =
                *reinterpret_cast<const float4*>(src + 4 * e);
    }
    // ---- persistent B fragments (wave's N=64 slice): 32 frags = 128 regs
    s16x8 bv[4][8];
    const s16x8* Bp = reinterpret_cast<const s16x8*>(W1F);
    #pragma unroll
    for (int nf = 0; nf < 4; ++nf)
        #pragma unroll
        for (int ks = 0; ks < 8; ++ks)
            bv[nf][ks] = Bp[((w * 4 + nf) * 8 + ks) * 64 + l];
    float b1v[4];
    #pragma unroll
    for (int nf = 0; nf < 4; ++nf) b1v[nf] = b1[w * 64 + nf * 16 + (l & 15)];
    int rowg = l >> 4;
    float jmask[4];
    #pragma unroll
    for (int r = 0; r < 4; ++r) jmask[r] = (j0 + rowg * 4 + r) < NP ? 1.0f : 0.0f;
    float psum[4] = {0.f, 0.f, 0.f, 0.f};
    int kb = l >> 4;
    const float* Urow = &Upad[(l & 15) * 260 + kb * 8];
    const float* Vbb = V + (size_t)bb * NP * DH + kb * 8;
    __syncthreads();   // the only barrier

    for (int itl = 0; itl < nt; ++itl) {
        int i0 = (tile0 + itl) * 4;
        f32x4 acc[4][4];
        #pragma unroll
        for (int mf = 0; mf < 4; ++mf)
            #pragma unroll
            for (int nf = 0; nf < 4; ++nf)
                acc[mf][nf] = (f32x4){b1v[nf], b1v[nf], b1v[nf], b1v[nf]};

        #pragma unroll
        for (int ks = 0; ks < 8; ++ks) {
            float4 ua = *reinterpret_cast<const float4*>(Urow + ks * 32);
            float4 ub = *reinterpret_cast<const float4*>(Urow + ks * 32 + 4);
            #pragma unroll
            for (int mf = 0; mf < 4; ++mf) {
                int ic = i0 + mf; if (ic >= NP) ic = NP - 1;   // clamp, no OOB
                const float* vp = Vbb + (size_t)ic * DH + ks * 32;
                float4 va = *reinterpret_cast<const float4*>(vp);
                float4 vb = *reinterpret_cast<const float4*>(vp + 4);
                u32x4 aw;
                aw.x = pack2(lrelu(ua.x + va.x), lrelu(ua.y + va.y));
                aw.y = pack2(lrelu(ua.z + va.z), lrelu(ua.w + va.w));
                aw.z = pack2(lrelu(ub.x + vb.x), lrelu(ub.y + vb.y));
                aw.w = pack2(lrelu(ub.z + vb.z), lrelu(ub.w + vb.w));
                s16x8 af = __builtin_bit_cast(s16x8, aw);
                #pragma unroll
                for (int nf = 0; nf < 4; ++nf)
                    acc[mf][nf] = __builtin_amdgcn_mfma_f32_16x16x32_bf16(
                        af, bv[nf][ks], acc[mf][nf], 0, 0, 0);
            }
        }

        // ---- epilogue: lrelu + fma-masked row-sum (wave-uniform mf skip)
        #pragma unroll
        for (int mf = 0; mf < 4; ++mf) {
            if (i0 + mf < NP) {
                #pragma unroll
                for (int r = 0; r < 4; ++r) {
                    #pragma unroll
                    for (int nf = 0; nf < 4; ++nf) {
                        float a = acc[mf][nf][r];
                        float h = fmaxf(a, 0.01f * a);
                        psum[nf] = fmaf(h, jmask[r], psum[nf]);
                    }
                }
            }
        }
    }

    // ---- block-level reduce + one atomicAdd set
    #pragma unroll
    for (int nf = 0; nf < 4; ++nf) {
        psum[nf] += __shfl_xor(psum[nf], 16);
        psum[nf] += __shfl_xor(psum[nf], 32);
    }
    if (l < 16) {
        #pragma unroll
        for (int nf = 0; nf < 4; ++nf)
            atomicAdd(&accg[bb * DH + w * 64 + nf * 16 + l], psum[nf]);
    }
}

// ---------------------------------------------------------------------------
// K3: out[b,o] = (accg[b,:]/P^2) @ Wout + bout
__global__ void out_kernel(const float* __restrict__ accg, const float* __restrict__ Wout,
                           const float* __restrict__ bout, float* __restrict__ out) {
    int bb = blockIdx.x;
    int o = threadIdx.x;  // 0..127
    float s = 0.f;
    for (int n = 0; n < DH; ++n)
        s = fmaf(accg[bb * DH + n], Wout[n * 128 + o], s);
    out[bb * 128 + o] = s * (1.0f / 50625.0f) + bout[o];
}

// ---------------------------------------------------------------------------
extern "C" void kernel_launch(void* const* d_in, const int* in_sizes, int n_in,
                              void* d_out, int out_size, void* d_ws, size_t ws_size,
                              hipStream_t stream) {
    const float* x    = (const float*)d_in[0];
    const float* W0   = (const float*)d_in[1];
    const float* b0   = (const float*)d_in[2];
    const float* W1   = (const float*)d_in[3];
    const float* b1   = (const float*)d_in[4];
    const float* Wout = (const float*)d_in[5];
    const float* bout = (const float*)d_in[6];
    float* out = (float*)d_out;

    char* ws = (char*)d_ws;
    float*    U    = (float*)(ws);                            // 8*225*256*4 = 1,843,200 B
    float*    V    = (float*)(ws + 1843200);                  // 1,843,200 B
    uint16_t* W1F  = (uint16_t*)(ws + 2 * 1843200);           // 131,072 B
    float*    accg = (float*)(ws + 2 * 1843200 + 131072);     // 8*256*4 = 8,192 B

    prep_kernel<<<392, 256, 0, stream>>>(x, W0, b0, W1, U, V, W1F, accg);
    main_kernel<<<NB * 15 * 12, 256, 0, stream>>>(U, V, W1F, b1, accg);
    out_kernel<<<NB, 128, 0, stream>>>(accg, Wout, bout, out);
}